// Round 1
// baseline (135.442 us; speedup 1.0000x reference)
//
#include <hip/hip_runtime.h>

#define RCUT 6.0f

__device__ __forceinline__ float fast_tanh(float x) {
    float e = __expf(2.0f * x);              // inf for large x -> tanh=1
    return 1.0f - 2.0f * __builtin_amdgcn_rcpf(e + 1.0f);
}

// ---------------- Kernel 1: per-atom neighbor scan + embed MLP + G + Feat ----
__global__ __launch_bounds__(128) void k_embed(
    const float* __restrict__ coord, const float* __restrict__ box,
    const float* __restrict__ srmean, const float* __restrict__ srstd,
    const float* __restrict__ xrsrstd, const float* __restrict__ Gbias,
    const float* __restrict__ eW0, const float* __restrict__ eb0,
    const float* __restrict__ eW1, const float* __restrict__ eb1,
    const float* __restrict__ eW2, const float* __restrict__ eb2,
    const int* __restrict__ n1p, float* __restrict__ feat, int N)
{
    const int n   = blockIdx.x;
    const int tid = threadIdx.x;
    const int n1  = *n1p;
    const int ti  = (n >= n1) ? 1 : 0;

    __shared__ float s_w[5376];            // all embed weights for row type ti
    __shared__ float s_e[128 * 65];        // e tile, padded rows (bank-conflict free)
    __shared__ float s_coef[4 * 128];      // per-pair coeffs (srbias, Rx, Ry, Rz)
    __shared__ unsigned short s_nbr[1024]; // compact neighbor list
    __shared__ float s_g4[256];            // G[4][64]
    __shared__ int   s_cnt;

    float* sw0  = s_w;          // [2][16]
    float* sb0  = s_w + 32;     // [2][16]
    float* sw1  = s_w + 64;     // [2][16][32]
    float* sb1  = s_w + 1088;   // [2][32]
    float* sw2t = s_w + 1152;   // [2][64][32]  (transposed W2)
    float* sb2  = s_w + 5248;   // [2][64]

    for (int t = tid; t < 32; t += 128) { int j = t >> 4, f = t & 15;
        sw0[t] = eW0[(2 * ti + j) * 16 + f]; sb0[t] = eb0[(2 * ti + j) * 16 + f]; }
    for (int t = tid; t < 1024; t += 128) { int j = t >> 9, r = t & 511;
        sw1[t] = eW1[(2 * ti + j) * 512 + r]; }
    for (int t = tid; t < 64; t += 128) { int j = t >> 5, g = t & 31;
        sb1[t] = eb1[(2 * ti + j) * 32 + g]; }
    for (int t = tid; t < 4096; t += 128) { int j = t >> 11, r = t & 2047, c = r >> 5, g = r & 31;
        sw2t[t] = eW2[(2 * ti + j) * 2048 + g * 64 + c]; }
    for (int t = tid; t < 128; t += 128) { int j = t >> 6, c = t & 63;
        sb2[t] = eb2[(2 * ti + j) * 64 + c]; }

    const float Lx = box[0], Ly = box[4], Lz = box[8];
    const float iLx = 1.0f / Lx, iLy = 1.0f / Ly, iLz = 1.0f / Lz;
    const float xn = coord[n], yn = coord[N + n], zn = coord[2 * N + n];

    // deterministic compacted neighbor scan (wave 0 only, m ascending)
    if (tid < 64) {
        int base = 0;
        for (int m0 = 0; m0 < N; m0 += 64) {
            int m = m0 + tid;
            float dx = coord[m] - xn;         dx -= Lx * rintf(dx * iLx);
            float dy = coord[N + m] - yn;     dy -= Ly * rintf(dy * iLy);
            float dz = coord[2 * N + m] - zn; dz -= Lz * rintf(dz * iLz);
            float r2 = dx * dx + dy * dy + dz * dz;
            bool pred = (r2 < RCUT * RCUT) && (m != n);
            unsigned long long bal = __ballot(pred);
            int pos = (int)__popcll(bal & ((1ull << tid) - 1ull));
            if (pred) s_nbr[base + pos] = (unsigned short)m;
            base += (int)__popcll(bal);
        }
        if (tid == 0) s_cnt = base;
    }
    __syncthreads();
    const int cnt = s_cnt;

    const float srm  = srmean[ti];
    const float isrs = 1.0f / srstd[ti];
    const float ixrs = 1.0f / xrsrstd[ti];

    float accA = 0.0f, accB = 0.0f;            // slots (k0,c0) and (k0+2,c0)
    const int c0 = tid & 63, k0 = tid >> 6;

    const int ntiles = (cnt + 127) >> 7;
    for (int t = 0; t < ntiles; t++) {
        __syncthreads();   // protect s_e/s_coef from previous stage-2 readers
        {   // ---- stage 1: per-pair MLP -> s_e, coeffs -> s_coef
            const int p = (t << 7) + tid;
            const bool valid = p < cnt;
            int m = valid ? (int)s_nbr[p] : ((n + 1) & (N - 1));
            float dx = coord[m] - xn;         dx -= Lx * rintf(dx * iLx);
            float dy = coord[N + m] - yn;     dy -= Ly * rintf(dy * iLy);
            float dz = coord[2 * N + m] - zn; dz -= Lz * rintf(dz * iLz);
            float r2 = dx * dx + dy * dy + dz * dz;
            float r  = sqrtf(r2);
            float rinv = __builtin_amdgcn_rcpf(r);
            float u  = r * (1.0f / RCUT);
            float u3 = u * u * u;
            float sw_ = ((-6.0f * u + 15.0f) * u - 10.0f) * u3 + 1.0f;
            if (!valid) sw_ = 0.0f;
            float sr  = sw_ * rinv;
            float srn = (sr - srm) * isrs;
            float csr = valid ? sr * isrs : 0.0f;
            float crs = valid ? (sr * rinv * ixrs + 1e-15f) : 0.0f;
            s_coef[tid]       = csr;
            s_coef[128 + tid] = crs * dx;
            s_coef[256 + tid] = crs * dy;
            s_coef[384 + tid] = crs * dz;

            int j = (m >= n1) ? 1 : 0;
            const float* w0  = sw0 + j * 16;
            const float* bb0 = sb0 + j * 16;
            float h0[16];
            #pragma unroll
            for (int f = 0; f < 16; f++) h0[f] = fast_tanh(fmaf(srn, w0[f], bb0[f]));

            float h1[32];
            const float* bb1 = sb1 + j * 32;
            #pragma unroll
            for (int g = 0; g < 32; g++) h1[g] = bb1[g];
            const float4* w1v = (const float4*)(sw1 + j * 512);
            #pragma unroll
            for (int f = 0; f < 16; f++) {
                float hf = h0[f];
                #pragma unroll
                for (int g4 = 0; g4 < 8; g4++) {
                    float4 w = w1v[f * 8 + g4];
                    h1[g4 * 4 + 0] = fmaf(hf, w.x, h1[g4 * 4 + 0]);
                    h1[g4 * 4 + 1] = fmaf(hf, w.y, h1[g4 * 4 + 1]);
                    h1[g4 * 4 + 2] = fmaf(hf, w.z, h1[g4 * 4 + 2]);
                    h1[g4 * 4 + 3] = fmaf(hf, w.w, h1[g4 * 4 + 3]);
                }
            }
            #pragma unroll
            for (int g = 0; g < 32; g++) h1[g] = fast_tanh(h1[g]);

            const float4* w2v = (const float4*)(sw2t + j * 2048);
            const float* bb2 = sb2 + j * 64;
            float* erow = s_e + tid * 65;
            #pragma unroll 8
            for (int c = 0; c < 64; c++) {
                float a = bb2[c];
                #pragma unroll
                for (int g4 = 0; g4 < 8; g4++) {
                    float4 w = w2v[c * 8 + g4];
                    a = fmaf(h1[g4 * 4 + 0], w.x, a);
                    a = fmaf(h1[g4 * 4 + 1], w.y, a);
                    a = fmaf(h1[g4 * 4 + 2], w.z, a);
                    a = fmaf(h1[g4 * 4 + 3], w.w, a);
                }
                erow[c] = fast_tanh(a);
            }
        }
        __syncthreads();
        // ---- stage 2: acc[k][c] += coeff[k][nb] * e[nb][c]
        const int tc = min(128, cnt - (t << 7));
        const float* ek = s_e + c0;
        #pragma unroll 4
        for (int nb = 0; nb < tc; nb++) {
            float e = ek[nb * 65];
            accA = fmaf(s_coef[k0 * 128 + nb],       e, accA);
            accB = fmaf(s_coef[(k0 + 2) * 128 + nb], e, accB);
        }
    }

    // ---- epilogue: G then Feat
    {
        float gA = accA * (1.0f / 64.0f);
        float gB = accB * (1.0f / 64.0f);
        if (k0 == 0) gA += Gbias[c0];
        s_g4[k0 * 64 + c0]       = gA;
        s_g4[(k0 + 2) * 64 + c0] = gB;
    }
    __syncthreads();
    float* out = feat + (size_t)n * 1024 + tid * 8;
    const int o0 = tid * 8;
    #pragma unroll
    for (int q = 0; q < 8; q++) {
        int o = o0 + q, a = o >> 6, c = o & 63;
        float s = 0.0f;
        #pragma unroll
        for (int k = 0; k < 4; k++) s = fmaf(s_g4[k * 64 + c], s_g4[k * 64 + a], s);
        out[q] = s;
    }
}

// ---------------- Kernel 2: fit net (4 atoms / block) + energy reduction -----
__global__ __launch_bounds__(256) void k_fit(
    const float* __restrict__ feat,
    const float* __restrict__ W0, const float* __restrict__ b0,
    const float* __restrict__ W1, const float* __restrict__ b1,
    const float* __restrict__ W2, const float* __restrict__ b2,
    const float* __restrict__ Ebias, const int* __restrict__ n1p,
    float* __restrict__ out)
{
    __shared__ float s_f[4 * 1024];
    __shared__ float s_h[4 * 128];
    __shared__ float s_h1[4 * 128];
    __shared__ float s_part[8];
    const int tid = threadIdx.x;
    const int nb0 = blockIdx.x * 4;
    const int i = (nb0 >= *n1p) ? 1 : 0;

    for (int t = tid; t < 4096; t += 256) s_f[t] = feat[(size_t)nb0 * 1024 + t];
    __syncthreads();

    const int f = tid & 127, s2 = tid >> 7;     // thread handles atoms s2, s2+2
    const float* w0p = W0 + (size_t)i * 131072 + f;
    float a0 = b0[i * 128 + f], a1 = a0;
    const float* fr0 = s_f + s2 * 1024;
    const float* fr1 = s_f + (s2 + 2) * 1024;
    #pragma unroll 8
    for (int x = 0; x < 1024; x++) {
        float w = w0p[x * 128];
        a0 = fmaf(fr0[x], w, a0);
        a1 = fmaf(fr1[x], w, a1);
    }
    s_h[s2 * 128 + f]       = fast_tanh(a0);
    s_h[(s2 + 2) * 128 + f] = fast_tanh(a1);
    __syncthreads();

    const float* w1p = W1 + (size_t)i * 16384 + f;
    a0 = b1[i * 128 + f]; a1 = a0;
    const float* hr0 = s_h + s2 * 128;
    const float* hr1 = s_h + (s2 + 2) * 128;
    #pragma unroll 8
    for (int g = 0; g < 128; g++) {
        float w = w1p[g * 128];
        a0 = fmaf(hr0[g], w, a0);
        a1 = fmaf(hr1[g], w, a1);
    }
    s_h1[s2 * 128 + f]       = fast_tanh(a0);
    s_h1[(s2 + 2) * 128 + f] = fast_tanh(a1);
    __syncthreads();

    float w2 = W2[i * 128 + f];
    float p0 = s_h1[s2 * 128 + f] * w2;
    float p1 = s_h1[(s2 + 2) * 128 + f] * w2;
    #pragma unroll
    for (int msk = 1; msk < 64; msk <<= 1) {
        p0 += __shfl_xor(p0, msk);
        p1 += __shfl_xor(p1, msk);
    }
    int w = tid >> 6;
    if ((tid & 63) == 0) { s_part[w * 2] = p0; s_part[w * 2 + 1] = p1; }
    __syncthreads();
    if (tid == 0) {
        float e0 = s_part[0] + s_part[2];
        float e2 = s_part[1] + s_part[3];
        float e1 = s_part[4] + s_part[6];
        float e3 = s_part[5] + s_part[7];
        atomicAdd(out, e0 + e1 + e2 + e3 + 4.0f * (b2[i] + Ebias[i]));
    }
}

extern "C" void kernel_launch(void* const* d_in, const int* in_sizes, int n_in,
                              void* d_out, int out_size, void* d_ws, size_t ws_size,
                              hipStream_t stream) {
    const float* coord   = (const float*)d_in[0];
    const float* box     = (const float*)d_in[1];
    const float* srmean  = (const float*)d_in[2];
    const float* srstd   = (const float*)d_in[3];
    const float* xrsrstd = (const float*)d_in[4];
    const float* Gbias   = (const float*)d_in[5];
    const float* Ebias   = (const float*)d_in[6];
    const float* eW0     = (const float*)d_in[7];
    const float* eb0     = (const float*)d_in[8];
    const float* eW1     = (const float*)d_in[9];
    const float* eb1     = (const float*)d_in[10];
    const float* eW2     = (const float*)d_in[11];
    const float* eb2     = (const float*)d_in[12];
    const float* fW0     = (const float*)d_in[13];
    const float* fb0     = (const float*)d_in[14];
    const float* fW1     = (const float*)d_in[15];
    const float* fb1     = (const float*)d_in[16];
    const float* fW2     = (const float*)d_in[17];
    const float* fb2     = (const float*)d_in[18];
    const int*   n1p     = (const int*)d_in[19];

    const int N = in_sizes[0] / 3;          // 1024
    float* featbuf = (float*)d_ws;          // N*1024 f32 = 4 MB

    hipMemsetAsync(d_out, 0, sizeof(float), stream);
    k_embed<<<N, 128, 0, stream>>>(coord, box, srmean, srstd, xrsrstd, Gbias,
                                   eW0, eb0, eW1, eb1, eW2, eb2, n1p, featbuf, N);
    k_fit<<<N / 4, 256, 0, stream>>>(featbuf, fW0, fb0, fW1, fb1, fW2, fb2,
                                     Ebias, n1p, (float*)d_out);
}

// Round 3
// 68.198 us; speedup vs baseline: 1.9860x; 1.9860x over previous
//
#include <hip/hip_runtime.h>

#define RCUT 6.0f

typedef _Float16 h2 __attribute__((ext_vector_type(2)));

__device__ __forceinline__ float fast_tanh(float x) {
    float e = __expf(2.0f * x);              // inf for large x -> tanh=1
    return 1.0f - 2.0f * __builtin_amdgcn_rcpf(e + 1.0f);
}

#if __has_builtin(__builtin_amdgcn_fdot2)
__device__ __forceinline__ float dot2(h2 a, h2 b, float c) {
    return __builtin_amdgcn_fdot2(a, b, c, false);
}
#else
__device__ __forceinline__ float dot2(h2 a, h2 b, float c) {
    return (float)a.x * (float)b.x + (float)a.y * (float)b.y + c;
}
#endif

__device__ __forceinline__ h2 pkh(float a, float b) {
#if __has_builtin(__builtin_amdgcn_cvt_pkrtz)
    union { __fp16 __attribute__((ext_vector_type(2))) r; h2 h; } u;
    u.r = __builtin_amdgcn_cvt_pkrtz(a, b);
    return u.h;
#else
    h2 r; r.x = (_Float16)a; r.y = (_Float16)b; return r;
#endif
}

// ---------------- Kernel 1: per-atom neighbor scan + embed MLP + G + Feat ----
// 256 threads = 4 waves. Stage 1: thread = (pair p = tid&127, c-half = tid>>7).
// Stage 2: thread = (k = tid>>6, c = tid&63).
__global__ __launch_bounds__(256, 4) void k_embed(
    const float* __restrict__ coord, const float* __restrict__ box,
    const float* __restrict__ srmean, const float* __restrict__ srstd,
    const float* __restrict__ xrsrstd, const float* __restrict__ Gbias,
    const float* __restrict__ eW0, const float* __restrict__ eb0,
    const float* __restrict__ eW1, const float* __restrict__ eb1,
    const float* __restrict__ eW2, const float* __restrict__ eb2,
    const int* __restrict__ n1p, float* __restrict__ feat, int N)
{
    const int n   = blockIdx.x;
    const int tid = threadIdx.x;
    const int n1  = *n1p;
    const int ti  = (n >= n1) ? 1 : 0;

    __shared__ struct {
        float    w0[2][16], b0[2][16];
        _Float16 w1t[2][32][16];     // [j][g][f]  (16B-aligned rows)
        float    b1[2][32];
        _Float16 w2t[2][64][32];     // [j][c][g]  (64B rows)
        float    b2[2][64];
    } sw;
    __shared__ h2 s_e2[128][33];     // e tile, fp16, padded rows
    __shared__ float s_coef[4][128]; // srbias, Rx, Ry, Rz per pair
    __shared__ unsigned short s_nbr[512];
    __shared__ float s_g4[256];      // G[4][64]
    __shared__ int   s_cnt;

    // ---- weight staging (fp16 for W1/W2, transposed) ----
    for (int t = tid; t < 32; t += 256) { int j = t >> 4, f = t & 15;
        sw.w0[j][f] = eW0[(2 * ti + j) * 16 + f];
        sw.b0[j][f] = eb0[(2 * ti + j) * 16 + f]; }
    for (int t = tid; t < 1024; t += 256) { int j = t >> 9, r = t & 511, f = r >> 5, g = r & 31;
        sw.w1t[j][g][f] = (_Float16)eW1[(2 * ti + j) * 512 + f * 32 + g]; }
    for (int t = tid; t < 64; t += 256) { int j = t >> 5, g = t & 31;
        sw.b1[j][g] = eb1[(2 * ti + j) * 32 + g]; }
    for (int t = tid; t < 4096; t += 256) { int j = t >> 11, r = t & 2047, g = r >> 6, c = r & 63;
        sw.w2t[j][c][g] = (_Float16)eW2[(2 * ti + j) * 2048 + g * 64 + c]; }
    for (int t = tid; t < 128; t += 256) { int j = t >> 6, c = t & 63;
        sw.b2[j][c] = eb2[(2 * ti + j) * 64 + c]; }

    const float Lx = box[0], Ly = box[4], Lz = box[8];
    const float iLx = 1.0f / Lx, iLy = 1.0f / Ly, iLz = 1.0f / Lz;
    const float xn = coord[n], yn = coord[N + n], zn = coord[2 * N + n];

    // ---- deterministic compacted neighbor scan (wave 0, m ascending) ----
    if (tid < 64) {
        int base = 0;
        for (int m0 = 0; m0 < N; m0 += 64) {
            int m = m0 + tid;
            float dx = coord[m] - xn;         dx -= Lx * rintf(dx * iLx);
            float dy = coord[N + m] - yn;     dy -= Ly * rintf(dy * iLy);
            float dz = coord[2 * N + m] - zn; dz -= Lz * rintf(dz * iLz);
            float r2 = dx * dx + dy * dy + dz * dz;
            bool pred = (r2 < RCUT * RCUT) && (m != n);
            unsigned long long bal = __ballot(pred);
            int pos = (int)__popcll(bal & ((1ull << tid) - 1ull));
            if (pred && (base + pos) < 512) s_nbr[base + pos] = (unsigned short)m;
            base += (int)__popcll(bal);
        }
        if (tid == 0) s_cnt = (base < 512) ? base : 512;
    }
    __syncthreads();
    const int cnt = s_cnt;

    const float srm  = srmean[ti];
    const float isrs = 1.0f / srstd[ti];
    const float ixrs = 1.0f / xrsrstd[ti];

    const int p  = tid & 127;   // stage-1 pair slot
    const int hh = tid >> 7;    // stage-1 c-half
    const int k2 = tid >> 6;    // stage-2 k
    const int c2 = tid & 63;    // stage-2 c
    const int dummy = (n + 1 < N) ? (n + 1) : 0;

    float acc0 = 0.0f, acc1 = 0.0f;

    const int ntiles = (cnt + 127) >> 7;
    for (int t = 0; t < ntiles; t++) {
        __syncthreads();   // protect s_e2/s_coef from previous stage-2 readers
        {   // ---- stage 1: per-pair MLP -> s_e2 (my 32 c's), coeffs -> s_coef
            const int pi = (t << 7) + p;
            const bool valid = pi < cnt;
            int m = valid ? (int)s_nbr[pi] : dummy;
            float dx = coord[m] - xn;         dx -= Lx * rintf(dx * iLx);
            float dy = coord[N + m] - yn;     dy -= Ly * rintf(dy * iLy);
            float dz = coord[2 * N + m] - zn; dz -= Lz * rintf(dz * iLz);
            float r2 = dx * dx + dy * dy + dz * dz;
            float r  = sqrtf(r2);
            float rinv = __builtin_amdgcn_rcpf(r);
            float u  = r * (1.0f / RCUT);
            float u3 = u * u * u;
            float sw_ = ((-6.0f * u + 15.0f) * u - 10.0f) * u3 + 1.0f;
            if (!valid) sw_ = 0.0f;
            float sr  = sw_ * rinv;
            float srn = (sr - srm) * isrs;
            if (hh == 0) {
                float csr = valid ? sr * isrs : 0.0f;
                float crs = valid ? (sr * rinv * ixrs + 1e-15f) : 0.0f;
                s_coef[0][p] = csr;
                s_coef[1][p] = crs * dx;
                s_coef[2][p] = crs * dy;
                s_coef[3][p] = crs * dz;
            }

            const int j = (m >= n1) ? 1 : 0;
            // W0: 1 -> 16
            float h0[16];
            #pragma unroll
            for (int f = 0; f < 16; f++)
                h0[f] = fast_tanh(fmaf(srn, sw.w0[j][f], sw.b0[j][f]));
            h2 h0p[8];
            #pragma unroll
            for (int q = 0; q < 8; q++) h0p[q] = pkh(h0[2 * q], h0[2 * q + 1]);

            // W1: 16 -> 32 (dot2)
            h2 h1p[16];
            #pragma unroll
            for (int g2 = 0; g2 < 16; g2++) {
                float hv[2];
                #pragma unroll
                for (int u_ = 0; u_ < 2; u_++) {
                    int g = 2 * g2 + u_;
                    union { float4 f4; h2 h[4]; } wa, wb;
                    wa.f4 = *(const float4*)&sw.w1t[j][g][0];
                    wb.f4 = *(const float4*)&sw.w1t[j][g][8];
                    float a = sw.b1[j][g];
                    #pragma unroll
                    for (int q = 0; q < 4; q++) a = dot2(h0p[q], wa.h[q], a);
                    #pragma unroll
                    for (int q = 0; q < 4; q++) a = dot2(h0p[4 + q], wb.h[q], a);
                    hv[u_] = fast_tanh(a);
                }
                h1p[g2] = pkh(hv[0], hv[1]);
            }

            // W2: 32 -> my 32 of 64 c's (dot2), store fp16 pairs
            const int cbase = hh * 32;
            #pragma unroll 2
            for (int cc = 0; cc < 32; cc += 2) {
                float ev[2];
                #pragma unroll
                for (int u_ = 0; u_ < 2; u_++) {
                    int c = cbase + cc + u_;
                    union { float4 f4; h2 h[4]; } w[4];
                    const float4* wp = (const float4*)&sw.w2t[j][c][0];
                    w[0].f4 = wp[0]; w[1].f4 = wp[1]; w[2].f4 = wp[2]; w[3].f4 = wp[3];
                    float a = sw.b2[j][c];
                    #pragma unroll
                    for (int q = 0; q < 16; q++) a = dot2(h1p[q], w[q >> 2].h[q & 3], a);
                    ev[u_] = fast_tanh(a);
                }
                s_e2[p][(cbase + cc) >> 1] = pkh(ev[0], ev[1]);
            }
        }
        __syncthreads();
        // ---- stage 2: acc[k][c] += coeff[k][nb] * e[nb][c]
        const int tc = min(128, cnt - (t << 7));
        const _Float16* eh = (const _Float16*)&s_e2[0][0];
        const float* cf = &s_coef[k2][0];
        int nb = 0;
        for (; nb + 1 < tc; nb += 2) {
            acc0 = fmaf(cf[nb],     (float)eh[nb * 66 + c2],       acc0);
            acc1 = fmaf(cf[nb + 1], (float)eh[(nb + 1) * 66 + c2], acc1);
        }
        if (nb < tc) acc0 = fmaf(cf[nb], (float)eh[nb * 66 + c2], acc0);
    }

    // ---- epilogue: G then Feat
    {
        float gv = (acc0 + acc1) * (1.0f / 64.0f);
        if (k2 == 0) gv += Gbias[c2];
        s_g4[k2 * 64 + c2] = gv;
    }
    __syncthreads();
    {
        const int o0 = tid * 4;
        const int a = o0 >> 6, cb = o0 & 63;
        float ga0 = s_g4[a],        ga1 = s_g4[64 + a];
        float ga2 = s_g4[128 + a],  ga3 = s_g4[192 + a];
        float4 o;
        float* op = (float*)&o;
        #pragma unroll
        for (int q = 0; q < 4; q++) {
            int c = cb + q;
            float s = ga0 * s_g4[c];
            s = fmaf(ga1, s_g4[64 + c], s);
            s = fmaf(ga2, s_g4[128 + c], s);
            s = fmaf(ga3, s_g4[192 + c], s);
            op[q] = s;
        }
        ((float4*)(feat + (size_t)n * 1024))[tid] = o;
    }
}

// ---------------- Kernel 2: fit net (2 atoms / block) + energy reduction -----
__global__ __launch_bounds__(256, 2) void k_fit(
    const float* __restrict__ feat,
    const float* __restrict__ W0, const float* __restrict__ b0,
    const float* __restrict__ W1, const float* __restrict__ b1,
    const float* __restrict__ W2, const float* __restrict__ b2,
    const float* __restrict__ Ebias, const int* __restrict__ n1p,
    float* __restrict__ out)
{
    __shared__ float s_f[2][1024];
    __shared__ float s_h[2][128];
    __shared__ float s_h1[2][128];
    __shared__ float s_part[4];
    const int tid = threadIdx.x;
    const int n0 = blockIdx.x * 2;
    const int n1 = *n1p;
    const int a = tid >> 7, f = tid & 127;
    const int ia = (n0 + a >= n1) ? 1 : 0;

    {   // stage feat rows (vectorized)
        const float4* src = (const float4*)(feat + (size_t)n0 * 1024);
        ((float4*)&s_f[0][0])[tid] = src[tid];
    }
    __syncthreads();

    // layer 0: 1024 -> 128, 4-way split accumulators
    const float* w0p = W0 + (size_t)ia * 131072 + f;
    const float* fr  = &s_f[a][0];
    float a0 = 0.f, a1 = 0.f, a2 = 0.f, a3 = 0.f;
    #pragma unroll 8
    for (int x = 0; x < 1024; x += 4) {
        a0 = fmaf(fr[x + 0], w0p[(x + 0) * 128], a0);
        a1 = fmaf(fr[x + 1], w0p[(x + 1) * 128], a1);
        a2 = fmaf(fr[x + 2], w0p[(x + 2) * 128], a2);
        a3 = fmaf(fr[x + 3], w0p[(x + 3) * 128], a3);
    }
    s_h[a][f] = fast_tanh((a0 + a1) + (a2 + a3) + b0[ia * 128 + f]);
    __syncthreads();

    // layer 1: 128 -> 128
    const float* w1p = W1 + (size_t)ia * 16384 + f;
    const float* hr  = &s_h[a][0];
    a0 = 0.f; a1 = 0.f;
    #pragma unroll 8
    for (int g = 0; g < 128; g += 2) {
        a0 = fmaf(hr[g],     w1p[g * 128],       a0);
        a1 = fmaf(hr[g + 1], w1p[(g + 1) * 128], a1);
    }
    s_h1[a][f] = fast_tanh(a0 + a1 + b1[ia * 128 + f]);
    __syncthreads();

    // layer 2 + reduction
    float pv = s_h1[a][f] * W2[ia * 128 + f];
    #pragma unroll
    for (int m = 1; m < 64; m <<= 1) pv += __shfl_xor(pv, m);
    int w = tid >> 6;
    if ((tid & 63) == 0) s_part[w] = pv;
    __syncthreads();
    if (tid == 0) {
        int i0 = (n0 >= n1) ? 1 : 0;
        int i1 = (n0 + 1 >= n1) ? 1 : 0;
        float e0 = s_part[0] + s_part[1] + b2[i0] + Ebias[i0];
        float e1 = s_part[2] + s_part[3] + b2[i1] + Ebias[i1];
        atomicAdd(out, e0 + e1);
    }
}

extern "C" void kernel_launch(void* const* d_in, const int* in_sizes, int n_in,
                              void* d_out, int out_size, void* d_ws, size_t ws_size,
                              hipStream_t stream) {
    const float* coord   = (const float*)d_in[0];
    const float* box     = (const float*)d_in[1];
    const float* srmean  = (const float*)d_in[2];
    const float* srstd   = (const float*)d_in[3];
    const float* xrsrstd = (const float*)d_in[4];
    const float* Gbias   = (const float*)d_in[5];
    const float* Ebias   = (const float*)d_in[6];
    const float* eW0     = (const float*)d_in[7];
    const float* eb0     = (const float*)d_in[8];
    const float* eW1     = (const float*)d_in[9];
    const float* eb1     = (const float*)d_in[10];
    const float* eW2     = (const float*)d_in[11];
    const float* eb2     = (const float*)d_in[12];
    const float* fW0     = (const float*)d_in[13];
    const float* fb0     = (const float*)d_in[14];
    const float* fW1     = (const float*)d_in[15];
    const float* fb1     = (const float*)d_in[16];
    const float* fW2     = (const float*)d_in[17];
    const float* fb2     = (const float*)d_in[18];
    const int*   n1p     = (const int*)d_in[19];

    const int N = in_sizes[0] / 3;          // 1024
    float* featbuf = (float*)d_ws;          // N*1024 f32 = 4 MB

    (void)hipMemsetAsync(d_out, 0, sizeof(float), stream);
    k_embed<<<N, 256, 0, stream>>>(coord, box, srmean, srstd, xrsrstd, Gbias,
                                   eW0, eb0, eW1, eb1, eW2, eb2, n1p, featbuf, N);
    k_fit<<<N / 2, 256, 0, stream>>>(featbuf, fW0, fb0, fW1, fb1, fW2, fb2,
                                     Ebias, n1p, (float*)d_out);
}